// Round 1
// baseline (11096.943 us; speedup 1.0000x reference)
//
#include <hip/hip_runtime.h>

#define B_   2
#define NS   4
#define T_   2048
#define D_   1024
#define E_   16
#define ND   4096
#define DFFN 1656
#define BT   4096
#define TD   (T_*D_)
#define EPS_ 1.1920929e-7f

static __device__ __forceinline__ float sigm(float x){ return 1.0f/(1.0f+__expf(-x)); }

// ---------------- routing + top-p gate ----------------
__global__ __launch_bounds__(256)
void k_route_gate(const float* __restrict__ s, const float* __restrict__ router_w,
                  float* __restrict__ gate_out)
{
    int tok = blockIdx.x;
    int b = tok >> 11, t = tok & (T_-1);
    const float* sbase = s + (size_t)b*NS*TD + (size_t)t*D_;
    __shared__ float rbuf[D_];
    __shared__ float part[16][17];
    __shared__ float logits[16];
    int tid = threadIdx.x;
    for (int dd = tid; dd < D_; dd += 256) {
        float acc = 0.f;
        #pragma unroll
        for (int j=0;j<NS;j++) acc += sbase[(size_t)j*TD + dd];
        rbuf[dd] = acc * 0.25f;
    }
    __syncthreads();
    int e = tid >> 4, m = tid & 15;
    const float* wr = router_w + (size_t)e*D_;
    float acc = 0.f;
    for (int k=m;k<D_;k+=16) acc += rbuf[k]*wr[k];
    part[e][m] = acc;
    __syncthreads();
    if (tid < 16) {
        float sum=0.f;
        for (int q=0;q<16;q++) sum += part[tid][q];
        logits[tid]=sum;
    }
    __syncthreads();
    if (tid==0) {
        float p[16];
        float mx=-1e30f;
        for (int i=0;i<16;i++) mx = fmaxf(mx, logits[i]);
        float sum=0.f;
        for (int i=0;i<16;i++){ p[i]=__expf(logits[i]-mx); sum+=p[i]; }
        float inv=1.0f/sum;
        for (int i=0;i<16;i++) p[i]*=inv;
        float* g = gate_out + (size_t)tok*E_;
        for (int i=0;i<16;i++){
            int rank=0; float csb=0.f;
            for (int k=0;k<16;k++){
                bool before = (p[k]>p[i]) || (p[k]==p[i] && k<i);
                if (before){ rank++; csb+=p[k]; }
            }
            bool msk = (rank==0) || (csb < 0.8f && rank < 4);
            g[i] = msk ? p[i] : 0.f;
        }
    }
}

// ---------------- inv RMS over flattened (n*d) ----------------
__global__ __launch_bounds__(256)
void k_inv_rms(const float* __restrict__ s, float* __restrict__ inv_rms)
{
    int tok=blockIdx.x; int b=tok>>11, t=tok&(T_-1);
    const float* sbase = s + (size_t)b*NS*TD + (size_t)t*D_;
    int tid=threadIdx.x;
    float ss=0.f;
    for (int k=tid;k<ND;k+=256){
        int j=k>>10, dd=k&1023;
        float v = sbase[(size_t)j*TD+dd];
        ss += v*v;
    }
    for (int off=32;off>0;off>>=1) ss += __shfl_down(ss, off, 64);
    __shared__ float red[4];
    if ((tid&63)==0) red[tid>>6]=ss;
    __syncthreads();
    if (tid==0)
        inv_rms[tok] = rsqrtf((red[0]+red[1]+red[2]+red[3])*(1.0f/ND) + EPS_);
}

// ---------------- fold mhc_norm_w * alpha into phi weights ----------------
__global__ __launch_bounds__(256)
void k_fold(const float* __restrict__ pw, const float* __restrict__ ow, const float* __restrict__ rw,
            const float* __restrict__ nw, const float* __restrict__ ap, const float* __restrict__ ao,
            const float* __restrict__ ar, float* __restrict__ Wall)
{
    int i = blockIdx.x*256 + threadIdx.x;
    if (i >= E_*24*ND) return;
    int k = i & (ND-1);
    int r = (i >> 12) % 24;
    int e = i / (24*ND);
    float w, a;
    if (r<4)      { w = pw[((size_t)e*4  + r     )*ND + k]; a = ap[e]; }
    else if (r<8) { w = ow[((size_t)e*4  + (r-4) )*ND + k]; a = ao[e]; }
    else          { w = rw[((size_t)e*16 + (r-8) )*ND + k]; a = ar[e]; }
    Wall[i] = w * a * nw[(size_t)e*ND + k];
}

// ---------------- dense GEMM: preact[tok][e*24+r] = inv_rms * <stream_vec, Wall> ----------------
__global__ __launch_bounds__(256)
void k_gemm_pre(const float* __restrict__ s, const float* __restrict__ Wall,
                const float* __restrict__ inv_rms, float* __restrict__ preact)
{
    const int m0 = blockIdx.x*64;
    const int n0 = blockIdx.y*64;
    __shared__ float As[16][68];
    __shared__ float Ws[16][68];
    const int tid=threadIdx.x;
    const int rl=tid>>2, kq=(tid&3)*4;
    const int tx=tid&15, ty=tid>>4;
    float acc[4][4]={};
    for (int k0=0;k0<ND;k0+=16){
        int tok=m0+rl, k=k0+kq;
        int b=tok>>11, t=tok&2047, j=k>>10, dd=k&1023;
        float4 av = *(const float4*)&s[(size_t)b*NS*TD + (size_t)j*TD + (size_t)t*D_ + dd];
        float4 wv = *(const float4*)&Wall[(size_t)(n0+rl)*ND + k];
        As[kq][rl]=av.x; As[kq+1][rl]=av.y; As[kq+2][rl]=av.z; As[kq+3][rl]=av.w;
        Ws[kq][rl]=wv.x; Ws[kq+1][rl]=wv.y; Ws[kq+2][rl]=wv.z; Ws[kq+3][rl]=wv.w;
        __syncthreads();
        #pragma unroll
        for (int kk=0;kk<16;kk++){
            const float4 a4 = *(const float4*)&As[kk][ty*4];
            const float4 w4 = *(const float4*)&Ws[kk][tx*4];
            const float aa[4]={a4.x,a4.y,a4.z,a4.w};
            const float ww[4]={w4.x,w4.y,w4.z,w4.w};
            #pragma unroll
            for (int i=0;i<4;i++)
                #pragma unroll
                for (int j2=0;j2<4;j2++)
                    acc[i][j2] += aa[i]*ww[j2];
        }
        __syncthreads();
    }
    #pragma unroll
    for (int i=0;i<4;i++){
        int m = m0+ty*4+i;
        float sc = inv_rms[m];
        float4 o = make_float4(acc[i][0]*sc, acc[i][1]*sc, acc[i][2]*sc, acc[i][3]*sc);
        *(float4*)&preact[(size_t)m*384 + n0 + tx*4] = o;
    }
}

// ---------------- activations + sinkhorn ----------------
__global__ __launch_bounds__(256)
void k_act(const float* __restrict__ preact, const float* __restrict__ b_pre,
           const float* __restrict__ b_post, const float* __restrict__ b_res,
           float* __restrict__ Hpre, float* __restrict__ Hpost, float* __restrict__ Hres)
{
    int i = blockIdx.x*256 + threadIdx.x;
    int tok = i & (BT-1);
    int e = i >> 12;
    const float* pr = preact + (size_t)tok*384 + e*24;
    float* hp = Hpre  + ((size_t)e*BT+tok)*4;
    float* ho = Hpost + ((size_t)e*BT+tok)*4;
    float* hr = Hres  + ((size_t)e*BT+tok)*16;
    #pragma unroll
    for (int r=0;r<4;r++) hp[r] = sigm(pr[r] + b_pre[e*4+r]);
    #pragma unroll
    for (int r=0;r<4;r++) ho[r] = 2.0f*sigm(pr[4+r] + b_post[e*4+r]);
    float Mv[16];
    #pragma unroll
    for (int r=0;r<16;r++) Mv[r] = __expf(pr[8+r] + b_res[e*16+r]);
    #pragma unroll
    for (int it=0; it<6; it++){
        #pragma unroll
        for (int r=0;r<4;r++){
            float ssum = Mv[4*r]+Mv[4*r+1]+Mv[4*r+2]+Mv[4*r+3];
            float inv = 1.0f/ssum;
            Mv[4*r]*=inv; Mv[4*r+1]*=inv; Mv[4*r+2]*=inv; Mv[4*r+3]*=inv;
        }
        #pragma unroll
        for (int c=0;c<4;c++){
            float ssum = Mv[c]+Mv[4+c]+Mv[8+c]+Mv[12+c];
            float inv = 1.0f/ssum;
            Mv[c]*=inv; Mv[4+c]*=inv; Mv[8+c]*=inv; Mv[12+c]*=inv;
        }
    }
    #pragma unroll
    for (int r=0;r<16;r++) hr[r]=Mv[r];
}

// ---------------- per-expert active-token list ----------------
__global__ __launch_bounds__(256)
void k_build(const float* __restrict__ gate, int* __restrict__ cnt, int* __restrict__ idx)
{
    int tok = blockIdx.x*256 + threadIdx.x;
    if (tok >= BT) return;
    #pragma unroll
    for (int e=0;e<E_;e++){
        if (gate[(size_t)tok*E_+e] > 0.0f){
            int p = atomicAdd(&cnt[e], 1);
            idx[(size_t)e*BT + p] = tok;
        }
    }
}

// ---------------- h = sum_j Hpre_j * stream_j ; hn = rms(h)*snw (compacted rows) ----------------
__global__ __launch_bounds__(256)
void k_hn(const float* __restrict__ s, const float* __restrict__ Hpre,
          const float* __restrict__ snw, const int* __restrict__ cnt,
          const int* __restrict__ idx, float* __restrict__ hn, int e)
{
    int p = blockIdx.x;
    if (p >= *cnt) return;
    int tok = idx[p];
    int b=tok>>11, t=tok&2047;
    const float* sbase = s + (size_t)b*NS*TD + (size_t)t*D_;
    const float* hp = Hpre + ((size_t)e*BT+tok)*4;
    float h0=hp[0], h1=hp[1], h2=hp[2], h3=hp[3];
    int tid=threadIdx.x;
    float hv[4]; float ss=0.f;
    #pragma unroll
    for (int u=0;u<4;u++){
        int dd = tid + u*256;
        float v = h0*sbase[dd] + h1*sbase[(size_t)TD+dd]
                + h2*sbase[(size_t)2*TD+dd] + h3*sbase[(size_t)3*TD+dd];
        hv[u]=v; ss += v*v;
    }
    for (int off=32;off>0;off>>=1) ss += __shfl_down(ss, off, 64);
    __shared__ float red[4];
    if ((tid&63)==0) red[tid>>6]=ss;
    __syncthreads();
    float tot = red[0]+red[1]+red[2]+red[3];
    float scale = rsqrtf(tot*(1.0f/D_) + EPS_);
    const float* sw = snw + (size_t)e*D_;
    #pragma unroll
    for (int u=0;u<4;u++){
        int dd = tid + u*256;
        hn[(size_t)p*D_+dd] = hv[u]*scale*sw[dd];
    }
}

// ---------------- generic NT GEMM on compacted rows ----------------
template<bool KB>
static __device__ __forceinline__ float4 ld4g(const float* p, int k, int K, bool rowok)
{
    float4 v = make_float4(0.f,0.f,0.f,0.f);
    if (rowok){
        if (!KB || k+3 < K) v = *(const float4*)(p + k);
        else {
            if (k   < K) v.x = p[k];
            if (k+1 < K) v.y = p[k+1];
            if (k+2 < K) v.z = p[k+2];
            if (k+3 < K) v.w = p[k+3];
        }
    }
    return v;
}

// EPI: 0 = silu, 1 = sigmoid, 2 = multiply by aux[m][n]
template<int EPI, bool NB, bool KB>
__global__ __launch_bounds__(256)
void k_gemm(const float* __restrict__ A, const float* __restrict__ W,
            float* __restrict__ C, const float* __restrict__ aux,
            const int* __restrict__ cnt, int N, int K, int ldc)
{
    const int Mact = *cnt;
    const int m0 = blockIdx.x*64;
    if (m0 >= Mact) return;
    const int n0 = blockIdx.y*64;
    __shared__ float As[16][68];
    __shared__ float Ws[16][68];
    const int tid=threadIdx.x;
    const int rl=tid>>2, kq=(tid&3)*4;
    const int tx=tid&15, ty=tid>>4;
    float acc[4][4]={};
    for (int k0=0;k0<K;k0+=16){
        int am=m0+rl, wn=n0+rl;
        float4 av = ld4g<KB>(A + (size_t)am*K, k0+kq, K, am<Mact);
        float4 wv = ld4g<KB>(W + (size_t)wn*K, k0+kq, K, (!NB) || (wn<N));
        As[kq][rl]=av.x; As[kq+1][rl]=av.y; As[kq+2][rl]=av.z; As[kq+3][rl]=av.w;
        Ws[kq][rl]=wv.x; Ws[kq+1][rl]=wv.y; Ws[kq+2][rl]=wv.z; Ws[kq+3][rl]=wv.w;
        __syncthreads();
        #pragma unroll
        for (int kk=0;kk<16;kk++){
            const float4 a4 = *(const float4*)&As[kk][ty*4];
            const float4 w4 = *(const float4*)&Ws[kk][tx*4];
            const float aa[4]={a4.x,a4.y,a4.z,a4.w};
            const float ww[4]={w4.x,w4.y,w4.z,w4.w};
            #pragma unroll
            for (int i=0;i<4;i++)
                #pragma unroll
                for (int j=0;j<4;j++)
                    acc[i][j] += aa[i]*ww[j];
        }
        __syncthreads();
    }
    #pragma unroll
    for (int i=0;i<4;i++){
        const int m = m0+ty*4+i;
        if (m >= Mact) continue;
        #pragma unroll
        for (int j=0;j<4;j++){
            const int n = n0+tx*4+j;
            if (NB && n>=N) continue;
            float v = acc[i][j];
            if (EPI==0)      v = v*sigm(v);
            else if (EPI==1) v = sigm(v);
            else             v = v*aux[(size_t)m*ldc + n];
            C[(size_t)m*ldc + n] = v;
        }
    }
}

// ---------------- dual GEMM: P = silu(A@Wg^T) * (A@Wu^T), N=DFFN, K=D ----------------
__global__ __launch_bounds__(256)
void k_gemm_dual(const float* __restrict__ A, const float* __restrict__ Wg,
                 const float* __restrict__ Wu, float* __restrict__ P,
                 const int* __restrict__ cnt)
{
    const int Mact = *cnt;
    const int m0 = blockIdx.x*64;
    if (m0 >= Mact) return;
    const int n0 = blockIdx.y*64;
    __shared__ float As[16][68];
    __shared__ float Gs[16][68];
    __shared__ float Us[16][68];
    const int tid=threadIdx.x;
    const int rl=tid>>2, kq=(tid&3)*4;
    const int tx=tid&15, ty=tid>>4;
    float ag[4][4]={}, au[4][4]={};
    for (int k0=0;k0<D_;k0+=16){
        int am=m0+rl, wn=n0+rl;
        float4 av = (am<Mact) ? *(const float4*)&A[(size_t)am*D_ + k0+kq] : make_float4(0.f,0.f,0.f,0.f);
        float4 gv, uv;
        if (wn < DFFN){
            gv = *(const float4*)&Wg[(size_t)wn*D_ + k0+kq];
            uv = *(const float4*)&Wu[(size_t)wn*D_ + k0+kq];
        } else { gv = make_float4(0.f,0.f,0.f,0.f); uv = gv; }
        As[kq][rl]=av.x; As[kq+1][rl]=av.y; As[kq+2][rl]=av.z; As[kq+3][rl]=av.w;
        Gs[kq][rl]=gv.x; Gs[kq+1][rl]=gv.y; Gs[kq+2][rl]=gv.z; Gs[kq+3][rl]=gv.w;
        Us[kq][rl]=uv.x; Us[kq+1][rl]=uv.y; Us[kq+2][rl]=uv.z; Us[kq+3][rl]=uv.w;
        __syncthreads();
        #pragma unroll
        for (int kk=0;kk<16;kk++){
            const float4 a4 = *(const float4*)&As[kk][ty*4];
            const float4 g4 = *(const float4*)&Gs[kk][tx*4];
            const float4 u4 = *(const float4*)&Us[kk][tx*4];
            const float aa[4]={a4.x,a4.y,a4.z,a4.w};
            const float gg[4]={g4.x,g4.y,g4.z,g4.w};
            const float uu[4]={u4.x,u4.y,u4.z,u4.w};
            #pragma unroll
            for (int i=0;i<4;i++)
                #pragma unroll
                for (int j=0;j<4;j++){
                    ag[i][j] += aa[i]*gg[j];
                    au[i][j] += aa[i]*uu[j];
                }
        }
        __syncthreads();
    }
    #pragma unroll
    for (int i=0;i<4;i++){
        const int m = m0+ty*4+i;
        if (m >= Mact) continue;
        #pragma unroll
        for (int j=0;j<4;j++){
            const int n = n0+tx*4+j;
            if (n >= DFFN) continue;
            float g = ag[i][j];
            P[(size_t)m*DFFN + n] = g*sigm(g)*au[i][j];
        }
    }
}

// ---------------- accumulate: acc += g*(Hres@stream + Hpost*out) ----------------
__global__ __launch_bounds__(256)
void k_accum(const float* __restrict__ s, const float* __restrict__ gate,
             const float* __restrict__ Hres, const float* __restrict__ Hpost,
             const float* __restrict__ outc, const int* __restrict__ cnt,
             const int* __restrict__ idx, float* __restrict__ acc, int e)
{
    int p = blockIdx.x;
    if (p >= *cnt) return;
    int tok = idx[p];
    float g = gate[(size_t)tok*E_ + e];
    int b=tok>>11, t=tok&2047;
    const float* hr = Hres  + ((size_t)e*BT+tok)*16;
    const float* hp = Hpost + ((size_t)e*BT+tok)*4;
    float R[16], P4[4];
    #pragma unroll
    for (int r=0;r<16;r++) R[r]=hr[r];
    #pragma unroll
    for (int r=0;r<4;r++) P4[r]=hp[r];
    const float* sbase = s   + (size_t)b*NS*TD + (size_t)t*D_;
    float* abase       = acc + (size_t)b*NS*TD + (size_t)t*D_;
    const float* oc = outc + (size_t)p*D_;
    int tid=threadIdx.x;
    #pragma unroll
    for (int u=0;u<4;u++){
        int dd = tid + u*256;
        float s0=sbase[dd], s1=sbase[(size_t)TD+dd], s2=sbase[(size_t)2*TD+dd], s3=sbase[(size_t)3*TD+dd];
        float ov=oc[dd];
        #pragma unroll
        for (int i=0;i<4;i++){
            float v = R[i*4+0]*s0 + R[i*4+1]*s1 + R[i*4+2]*s2 + R[i*4+3]*s3 + P4[i]*ov;
            abase[(size_t)i*TD + dd] += g*v;
        }
    }
}

extern "C" void kernel_launch(void* const* d_in, const int* in_sizes, int n_in,
                              void* d_out, int out_size, void* d_ws, size_t ws_size,
                              hipStream_t stream)
{
    const float* s_in       = (const float*)d_in[0];
    const float* router_w   = (const float*)d_in[1];
    const float* mhc_norm_w = (const float*)d_in[2];
    const float* phi_pre_w  = (const float*)d_in[3];
    const float* phi_post_w = (const float*)d_in[4];
    const float* phi_res_w  = (const float*)d_in[5];
    const float* b_pre      = (const float*)d_in[6];
    const float* b_post     = (const float*)d_in[7];
    const float* b_res      = (const float*)d_in[8];
    const float* alpha_pre  = (const float*)d_in[9];
    const float* alpha_post = (const float*)d_in[10];
    const float* alpha_res  = (const float*)d_in[11];
    const float* sw_norm_w  = (const float*)d_in[12];
    const float* wd_w       = (const float*)d_in[13];
    const float* wu_w       = (const float*)d_in[14];
    const float* gate_w     = (const float*)d_in[15];
    const float* up_w       = (const float*)d_in[16];
    const float* down_w     = (const float*)d_in[17];

    float* out_stream = (float*)d_out;
    float* gate_out   = out_stream + (size_t)B_*NS*T_*D_;

    char* w = (char*)d_ws;
    int*   cnt     = (int*)w;   w += 256;
    int*   idx     = (int*)w;   w += (size_t)E_*BT*4;
    float* inv_rms = (float*)w; w += (size_t)BT*4;
    float* Wall    = (float*)w; w += (size_t)E_*24*ND*4;
    float* preact  = (float*)w; w += (size_t)BT*384*4;
    float* Hpre    = (float*)w; w += (size_t)E_*BT*4*4;
    float* Hpost   = (float*)w; w += (size_t)E_*BT*4*4;
    float* Hres    = (float*)w; w += (size_t)E_*BT*16*4;
    float* hn      = (float*)w; w += (size_t)BT*D_*4;
    float* Abuf    = (float*)w; w += (size_t)BT*D_*4;
    float* gsig    = (float*)w; w += (size_t)BT*D_*4;
    float* Pbuf    = (float*)w; w += (size_t)BT*DFFN*4;
    float* outc    = (float*)w; w += (size_t)BT*D_*4;

    hipMemsetAsync(d_out, 0, (size_t)B_*NS*T_*D_*4, stream);
    hipMemsetAsync(cnt, 0, 256, stream);

    k_route_gate<<<BT,256,0,stream>>>(s_in, router_w, gate_out);
    k_inv_rms<<<BT,256,0,stream>>>(s_in, inv_rms);
    {
        int tot = E_*24*ND;
        k_fold<<<(tot+255)/256,256,0,stream>>>(phi_pre_w, phi_post_w, phi_res_w,
                                               mhc_norm_w, alpha_pre, alpha_post, alpha_res, Wall);
    }
    k_gemm_pre<<<dim3(BT/64, 384/64),256,0,stream>>>(s_in, Wall, inv_rms, preact);
    k_act<<<(BT*E_)/256,256,0,stream>>>(preact, b_pre, b_post, b_res, Hpre, Hpost, Hres);
    k_build<<<BT/256,256,0,stream>>>(gate_out, cnt, idx);

    for (int e=0; e<E_; e++){
        k_hn<<<BT,256,0,stream>>>(s_in, Hpre, sw_norm_w, cnt+e, idx+(size_t)e*BT, hn, e);
        k_gemm<0,false,false><<<dim3(BT/64, D_/64),256,0,stream>>>(
            hn, wd_w + (size_t)e*D_*D_, Abuf, nullptr, cnt+e, D_, D_, D_);
        k_gemm<1,false,false><<<dim3(BT/64, D_/64),256,0,stream>>>(
            Abuf, wu_w + (size_t)e*D_*D_, gsig, nullptr, cnt+e, D_, D_, D_);
        k_gemm_dual<<<dim3(BT/64, 26),256,0,stream>>>(
            hn, gate_w + (size_t)e*DFFN*D_, up_w + (size_t)e*DFFN*D_, Pbuf, cnt+e);
        k_gemm<2,false,true><<<dim3(BT/64, D_/64),256,0,stream>>>(
            Pbuf, down_w + (size_t)e*D_*DFFN, outc, gsig, cnt+e, D_, DFFN, D_);
        k_accum<<<BT,256,0,stream>>>(s_in, gate_out, Hres, Hpost, outc, cnt+e, idx+(size_t)e*BT, out_stream, e);
    }
}

// Round 2
// 6852.625 us; speedup vs baseline: 1.6194x; 1.6194x over previous
//
#include <hip/hip_runtime.h>

#define B_   2
#define NS   4
#define T_   2048
#define D_   1024
#define E_   16
#define ND   4096
#define DFFN 1656
#define BT   4096
#define TD   (T_*D_)
#define EPS_ 1.1920929e-7f

typedef __bf16 bf16x8 __attribute__((ext_vector_type(8)));
typedef float  f32x4  __attribute__((ext_vector_type(4)));

static __device__ __forceinline__ float sigm(float x){ return 1.0f/(1.0f+__expf(-x)); }
static __device__ __forceinline__ unsigned short f2us(float x){
    return __builtin_bit_cast(unsigned short, (__bf16)x);
}
static __device__ __forceinline__ float us2f(unsigned short u){
    return (float)__builtin_bit_cast(__bf16, u);
}
static __device__ __forceinline__ ushort4 cvt4(float4 v){
    ushort4 r; r.x=f2us(v.x); r.y=f2us(v.y); r.z=f2us(v.z); r.w=f2us(v.w); return r;
}

// ---------------- routing + top-p gate ----------------
__global__ __launch_bounds__(256)
void k_route_gate(const float* __restrict__ s, const float* __restrict__ router_w,
                  float* __restrict__ gate_out)
{
    int tok = blockIdx.x;
    int b = tok >> 11, t = tok & (T_-1);
    const float* sbase = s + (size_t)b*NS*TD + (size_t)t*D_;
    __shared__ float rbuf[D_];
    __shared__ float part[16][17];
    __shared__ float logits[16];
    int tid = threadIdx.x;
    for (int dd = tid; dd < D_; dd += 256) {
        float acc = 0.f;
        #pragma unroll
        for (int j=0;j<NS;j++) acc += sbase[(size_t)j*TD + dd];
        rbuf[dd] = acc * 0.25f;
    }
    __syncthreads();
    int e = tid >> 4, m = tid & 15;
    const float* wr = router_w + (size_t)e*D_;
    float acc = 0.f;
    for (int k=m;k<D_;k+=16) acc += rbuf[k]*wr[k];
    part[e][m] = acc;
    __syncthreads();
    if (tid < 16) {
        float sum=0.f;
        for (int q=0;q<16;q++) sum += part[tid][q];
        logits[tid]=sum;
    }
    __syncthreads();
    if (tid==0) {
        float p[16];
        float mx=-1e30f;
        for (int i=0;i<16;i++) mx = fmaxf(mx, logits[i]);
        float sum=0.f;
        for (int i=0;i<16;i++){ p[i]=__expf(logits[i]-mx); sum+=p[i]; }
        float inv=1.0f/sum;
        for (int i=0;i<16;i++) p[i]*=inv;
        float* g = gate_out + (size_t)tok*E_;
        for (int i=0;i<16;i++){
            int rank=0; float csb=0.f;
            for (int k=0;k<16;k++){
                bool before = (p[k]>p[i]) || (p[k]==p[i] && k<i);
                if (before){ rank++; csb+=p[k]; }
            }
            bool msk = (rank==0) || (csb < 0.8f && rank < 4);
            g[i] = msk ? p[i] : 0.f;
        }
    }
}

// ---------------- inv RMS over flattened (n*d) ----------------
__global__ __launch_bounds__(256)
void k_inv_rms(const float* __restrict__ s, float* __restrict__ inv_rms)
{
    int tok=blockIdx.x; int b=tok>>11, t=tok&(T_-1);
    const float* sbase = s + (size_t)b*NS*TD + (size_t)t*D_;
    int tid=threadIdx.x;
    float ss=0.f;
    for (int k=tid;k<ND;k+=256){
        int j=k>>10, dd=k&1023;
        float v = sbase[(size_t)j*TD+dd];
        ss += v*v;
    }
    for (int off=32;off>0;off>>=1) ss += __shfl_down(ss, off, 64);
    __shared__ float red[4];
    if ((tid&63)==0) red[tid>>6]=ss;
    __syncthreads();
    if (tid==0)
        inv_rms[tok] = rsqrtf((red[0]+red[1]+red[2]+red[3])*(1.0f/ND) + EPS_);
}

// ---------------- fold mhc_norm_w * alpha into phi weights ----------------
__global__ __launch_bounds__(256)
void k_fold(const float* __restrict__ pw, const float* __restrict__ ow, const float* __restrict__ rw,
            const float* __restrict__ nw, const float* __restrict__ ap, const float* __restrict__ ao,
            const float* __restrict__ ar, float* __restrict__ Wall)
{
    int i = blockIdx.x*256 + threadIdx.x;
    if (i >= E_*24*ND) return;
    int k = i & (ND-1);
    int r = (i >> 12) % 24;
    int e = i / (24*ND);
    float w, a;
    if (r<4)      { w = pw[((size_t)e*4  + r     )*ND + k]; a = ap[e]; }
    else if (r<8) { w = ow[((size_t)e*4  + (r-4) )*ND + k]; a = ao[e]; }
    else          { w = rw[((size_t)e*16 + (r-8) )*ND + k]; a = ar[e]; }
    Wall[i] = w * a * nw[(size_t)e*ND + k];
}

// =====================================================================
// bf16 MFMA GEMM: C[M x N] = A[M x K](bf16) @ W[N x K](f32, cvt)^T
// 128x128 block tile, BK=32, 4 waves each 64x64 (4x4 of 16x16x32 MFMA).
// EPI: 1 = silu -> bf16 ; 2 = sigmoid -> bf16 ; 3 = * aux(bf16) -> bf16
// =====================================================================
template<int EPI>
__global__ __launch_bounds__(256)
void k_mm(const unsigned short* __restrict__ A, const float* __restrict__ W,
          unsigned short* __restrict__ C, const unsigned short* __restrict__ aux,
          const int* __restrict__ cnt, int N, int K, int ldc)
{
    const int Mact = *cnt;
    const int m0 = blockIdx.x*128;
    if (m0 >= Mact) return;
    const int n0 = blockIdx.y*128;

    __shared__ unsigned short As[128*40];
    __shared__ unsigned short Ws[128*40];

    const int tid = threadIdx.x;
    const int lane = tid & 63, w = tid >> 6;
    const int wm = (w>>1)*64, wn = (w&1)*64;
    const int lr = lane & 15, kg = lane >> 4;

    int aoff[4], boff[4];
    #pragma unroll
    for (int i=0;i<4;i++){ aoff[i] = (wm+i*16+lr)*40 + kg*8; boff[i] = (wn+i*16+lr)*40 + kg*8; }

    // A staging indices: 2 passes, row = tid>>2 (+64), kcol8 = (tid&3)*8
    const int ar0 = tid>>2, ak8 = (tid&3)*8;
    // W staging: row = tid>>1, half = (tid&1)*16
    const int wr0 = tid>>1, wh = (tid&1)*16;

    f32x4 acc[4][4] = {};

    for (int k0=0; k0<K; k0+=32){
        // ---- stage A (bf16 global -> LDS) ----
        #pragma unroll
        for (int p=0;p<2;p++){
            int row = ar0 + p*64;
            uint4 v = make_uint4(0u,0u,0u,0u);
            if (m0+row < Mact && k0+ak8+8 <= K)
                v = *(const uint4*)&A[(size_t)(m0+row)*K + k0 + ak8];
            *(uint4*)&As[row*40 + ak8] = v;
        }
        // ---- stage W (f32 global -> cvt -> LDS bf16) ----
        {
            int row = wr0;
            bool rv = (n0+row) < N;
            #pragma unroll
            for (int q=0;q<4;q++){
                int k = k0 + wh + q*4;
                float4 wv = make_float4(0.f,0.f,0.f,0.f);
                if (rv && k+4 <= K)
                    wv = *(const float4*)&W[(size_t)(n0+row)*K + k];
                *(ushort4*)&Ws[row*40 + wh + q*4] = cvt4(wv);
            }
        }
        __syncthreads();
        bf16x8 af[4], bw[4];
        #pragma unroll
        for (int i=0;i<4;i++) af[i] = *(const bf16x8*)(const void*)&As[aoff[i]];
        #pragma unroll
        for (int j=0;j<4;j++) bw[j] = *(const bf16x8*)(const void*)&Ws[boff[j]];
        #pragma unroll
        for (int i=0;i<4;i++)
            #pragma unroll
            for (int j=0;j<4;j++)
                acc[i][j] = __builtin_amdgcn_mfma_f32_16x16x32_bf16(af[i], bw[j], acc[i][j], 0,0,0);
        __syncthreads();
    }

    // ---- epilogue: C/D layout col=lane&15, row=kg*4+reg ----
    #pragma unroll
    for (int i=0;i<4;i++){
        #pragma unroll
        for (int r=0;r<4;r++){
            int gr = m0 + wm + i*16 + kg*4 + r;
            if (gr >= Mact) continue;
            #pragma unroll
            for (int j=0;j<4;j++){
                int gc = n0 + wn + j*16 + lr;
                if (gc >= N) continue;
                float v = acc[i][j][r];
                if (EPI==1)      v = v*sigm(v);
                else if (EPI==2) v = sigm(v);
                else             v = v*us2f(aux[(size_t)gr*ldc + gc]);
                C[(size_t)gr*ldc + gc] = f2us(v);
            }
        }
    }
}

// ---------------- pre-GEMM (MFMA): preact = inv_rms * (stream_flat @ Wall^T) ----------------
__global__ __launch_bounds__(256)
void k_mm_pre(const float* __restrict__ s, const float* __restrict__ W,
              const float* __restrict__ scale, float* __restrict__ C)
{
    const int m0 = blockIdx.x*128;
    const int n0 = blockIdx.y*128;

    __shared__ unsigned short As[128*40];
    __shared__ unsigned short Ws[128*40];

    const int tid = threadIdx.x;
    const int lane = tid & 63, w = tid >> 6;
    const int wm = (w>>1)*64, wn = (w&1)*64;
    const int lr = lane & 15, kg = lane >> 4;

    int aoff[4], boff[4];
    #pragma unroll
    for (int i=0;i<4;i++){ aoff[i] = (wm+i*16+lr)*40 + kg*8; boff[i] = (wn+i*16+lr)*40 + kg*8; }

    const int r0 = tid>>1, hh = (tid&1)*16;
    // A row -> stream address pieces (row = token)
    const int tok = m0 + r0;
    const int ab = tok >> 11, at = tok & 2047;
    const float* arow = s + (size_t)ab*NS*TD + (size_t)at*D_;

    f32x4 acc[4][4] = {};

    for (int k0=0; k0<ND; k0+=32){
        {   // stage A: f32 stream (k -> j*TD + dd) -> bf16 LDS
            int kb = k0 + hh;          // multiple of 16, chunk stays within one 1024 block
            int j = kb >> 10, dd = kb & 1023;
            const float* pa = arow + (size_t)j*TD + dd;
            #pragma unroll
            for (int q=0;q<4;q++){
                float4 av = *(const float4*)(pa + q*4);
                *(ushort4*)&As[r0*40 + hh + q*4] = cvt4(av);
            }
        }
        {   // stage W (Wall f32 [384][4096])
            #pragma unroll
            for (int q=0;q<4;q++){
                int k = k0 + hh + q*4;
                float4 wv = *(const float4*)&W[(size_t)(n0+r0)*ND + k];
                *(ushort4*)&Ws[r0*40 + hh + q*4] = cvt4(wv);
            }
        }
        __syncthreads();
        bf16x8 af[4], bw[4];
        #pragma unroll
        for (int i=0;i<4;i++) af[i] = *(const bf16x8*)(const void*)&As[aoff[i]];
        #pragma unroll
        for (int j=0;j<4;j++) bw[j] = *(const bf16x8*)(const void*)&Ws[boff[j]];
        #pragma unroll
        for (int i=0;i<4;i++)
            #pragma unroll
            for (int j=0;j<4;j++)
                acc[i][j] = __builtin_amdgcn_mfma_f32_16x16x32_bf16(af[i], bw[j], acc[i][j], 0,0,0);
        __syncthreads();
    }

    #pragma unroll
    for (int i=0;i<4;i++){
        #pragma unroll
        for (int r=0;r<4;r++){
            int gr = m0 + wm + i*16 + kg*4 + r;
            float sc = scale[gr];
            #pragma unroll
            for (int j=0;j<4;j++){
                int gc = n0 + wn + j*16 + lr;
                if (gc >= 384) continue;
                C[(size_t)gr*384 + gc] = acc[i][j][r]*sc;
            }
        }
    }
}

// ---------------- activations + sinkhorn ----------------
__global__ __launch_bounds__(256)
void k_act(const float* __restrict__ preact, const float* __restrict__ b_pre,
           const float* __restrict__ b_post, const float* __restrict__ b_res,
           float* __restrict__ Hpre, float* __restrict__ Hpost, float* __restrict__ Hres)
{
    int i = blockIdx.x*256 + threadIdx.x;
    int tok = i & (BT-1);
    int e = i >> 12;
    const float* pr = preact + (size_t)tok*384 + e*24;
    float* hp = Hpre  + ((size_t)e*BT+tok)*4;
    float* ho = Hpost + ((size_t)e*BT+tok)*4;
    float* hr = Hres  + ((size_t)e*BT+tok)*16;
    #pragma unroll
    for (int r=0;r<4;r++) hp[r] = sigm(pr[r] + b_pre[e*4+r]);
    #pragma unroll
    for (int r=0;r<4;r++) ho[r] = 2.0f*sigm(pr[4+r] + b_post[e*4+r]);
    float Mv[16];
    #pragma unroll
    for (int r=0;r<16;r++) Mv[r] = __expf(pr[8+r] + b_res[e*16+r]);
    #pragma unroll
    for (int it=0; it<6; it++){
        #pragma unroll
        for (int r=0;r<4;r++){
            float inv = 1.0f/(Mv[4*r]+Mv[4*r+1]+Mv[4*r+2]+Mv[4*r+3]);
            Mv[4*r]*=inv; Mv[4*r+1]*=inv; Mv[4*r+2]*=inv; Mv[4*r+3]*=inv;
        }
        #pragma unroll
        for (int c=0;c<4;c++){
            float inv = 1.0f/(Mv[c]+Mv[4+c]+Mv[8+c]+Mv[12+c]);
            Mv[c]*=inv; Mv[4+c]*=inv; Mv[8+c]*=inv; Mv[12+c]*=inv;
        }
    }
    #pragma unroll
    for (int r=0;r<16;r++) hr[r]=Mv[r];
}

// ---------------- per-expert active-token list ----------------
__global__ __launch_bounds__(256)
void k_build(const float* __restrict__ gate, int* __restrict__ cnt, int* __restrict__ idx)
{
    int tok = blockIdx.x*256 + threadIdx.x;
    if (tok >= BT) return;
    #pragma unroll
    for (int e=0;e<E_;e++){
        if (gate[(size_t)tok*E_+e] > 0.0f){
            int p = atomicAdd(&cnt[e], 1);
            idx[(size_t)e*BT + p] = tok;
        }
    }
}

// ---------------- h = sum_j Hpre_j*stream_j ; hn = rms(h)*snw -> bf16 ----------------
__global__ __launch_bounds__(256)
void k_hn(const float* __restrict__ s, const float* __restrict__ Hpre,
          const float* __restrict__ snw, const int* __restrict__ cnt,
          const int* __restrict__ idx, unsigned short* __restrict__ hn, int e)
{
    int p = blockIdx.x;
    if (p >= *cnt) return;
    int tok = idx[p];
    int b=tok>>11, t=tok&2047;
    const float* sbase = s + (size_t)b*NS*TD + (size_t)t*D_;
    const float* hp = Hpre + ((size_t)e*BT+tok)*4;
    float h0=hp[0], h1=hp[1], h2=hp[2], h3=hp[3];
    int tid=threadIdx.x;
    float hv[4]; float ss=0.f;
    #pragma unroll
    for (int u=0;u<4;u++){
        int dd = tid + u*256;
        float v = h0*sbase[dd] + h1*sbase[(size_t)TD+dd]
                + h2*sbase[(size_t)2*TD+dd] + h3*sbase[(size_t)3*TD+dd];
        hv[u]=v; ss += v*v;
    }
    for (int off=32;off>0;off>>=1) ss += __shfl_down(ss, off, 64);
    __shared__ float red[4];
    if ((tid&63)==0) red[tid>>6]=ss;
    __syncthreads();
    float tot = red[0]+red[1]+red[2]+red[3];
    float scale = rsqrtf(tot*(1.0f/D_) + EPS_);
    const float* sw = snw + (size_t)e*D_;
    #pragma unroll
    for (int u=0;u<4;u++){
        int dd = tid + u*256;
        hn[(size_t)p*D_+dd] = f2us(hv[u]*scale*sw[dd]);
    }
}

// ---------------- accumulate: acc += g*(Hres@stream + Hpost*out) ----------------
__global__ __launch_bounds__(256)
void k_accum(const float* __restrict__ s, const float* __restrict__ gate,
             const float* __restrict__ Hres, const float* __restrict__ Hpost,
             const unsigned short* __restrict__ outc, const int* __restrict__ cnt,
             const int* __restrict__ idx, float* __restrict__ acc, int e)
{
    int p = blockIdx.x;
    if (p >= *cnt) return;
    int tok = idx[p];
    float g = gate[(size_t)tok*E_ + e];
    int b=tok>>11, t=tok&2047;
    const float* hr = Hres  + ((size_t)e*BT+tok)*16;
    const float* hp = Hpost + ((size_t)e*BT+tok)*4;
    float R[16], P4[4];
    #pragma unroll
    for (int r=0;r<16;r++) R[r]=hr[r];
    #pragma unroll
    for (int r=0;r<4;r++) P4[r]=hp[r];
    const float* sbase = s   + (size_t)b*NS*TD + (size_t)t*D_;
    float* abase       = acc + (size_t)b*NS*TD + (size_t)t*D_;
    const unsigned short* oc = outc + (size_t)p*D_;
    int tid=threadIdx.x;
    #pragma unroll
    for (int u=0;u<4;u++){
        int dd = tid + u*256;
        float s0=sbase[dd], s1=sbase[(size_t)TD+dd], s2=sbase[(size_t)2*TD+dd], s3=sbase[(size_t)3*TD+dd];
        float ov=us2f(oc[dd]);
        #pragma unroll
        for (int i=0;i<4;i++){
            float v = R[i*4+0]*s0 + R[i*4+1]*s1 + R[i*4+2]*s2 + R[i*4+3]*s3 + P4[i]*ov;
            abase[(size_t)i*TD + dd] += g*v;
        }
    }
}

extern "C" void kernel_launch(void* const* d_in, const int* in_sizes, int n_in,
                              void* d_out, int out_size, void* d_ws, size_t ws_size,
                              hipStream_t stream)
{
    const float* s_in       = (const float*)d_in[0];
    const float* router_w   = (const float*)d_in[1];
    const float* mhc_norm_w = (const float*)d_in[2];
    const float* phi_pre_w  = (const float*)d_in[3];
    const float* phi_post_w = (const float*)d_in[4];
    const float* phi_res_w  = (const float*)d_in[5];
    const float* b_pre      = (const float*)d_in[6];
    const float* b_post     = (const float*)d_in[7];
    const float* b_res      = (const float*)d_in[8];
    const float* alpha_pre  = (const float*)d_in[9];
    const float* alpha_post = (const float*)d_in[10];
    const float* alpha_res  = (const float*)d_in[11];
    const float* sw_norm_w  = (const float*)d_in[12];
    const float* wd_w       = (const float*)d_in[13];
    const float* wu_w       = (const float*)d_in[14];
    const float* gate_w     = (const float*)d_in[15];
    const float* up_w       = (const float*)d_in[16];
    const float* down_w     = (const float*)d_in[17];

    float* out_stream = (float*)d_out;
    float* gate_out   = out_stream + (size_t)B_*NS*T_*D_;

    char* w = (char*)d_ws;
    int*   cnt     = (int*)w;   w += 256;
    int*   idx     = (int*)w;   w += (size_t)E_*BT*4;
    float* inv_rms = (float*)w; w += (size_t)BT*4;
    float* Wall    = (float*)w; w += (size_t)E_*24*ND*4;
    float* preact  = (float*)w; w += (size_t)BT*384*4;
    float* Hpre    = (float*)w; w += (size_t)E_*BT*4*4;
    float* Hpost   = (float*)w; w += (size_t)E_*BT*4*4;
    float* Hres    = (float*)w; w += (size_t)E_*BT*16*4;
    unsigned short* hn   = (unsigned short*)w; w += (size_t)BT*D_*2;
    unsigned short* Abuf = (unsigned short*)w; w += (size_t)BT*D_*2;
    unsigned short* gsig = (unsigned short*)w; w += (size_t)BT*D_*2;
    unsigned short* tmpP = (unsigned short*)w; w += (size_t)BT*DFFN*2;
    unsigned short* Pbuf = (unsigned short*)w; w += (size_t)BT*DFFN*2;
    unsigned short* outc = (unsigned short*)w; w += (size_t)BT*D_*2;

    hipMemsetAsync(d_out, 0, (size_t)B_*NS*T_*D_*4, stream);
    hipMemsetAsync(cnt, 0, 256, stream);

    k_route_gate<<<BT,256,0,stream>>>(s_in, router_w, gate_out);
    k_inv_rms<<<BT,256,0,stream>>>(s_in, inv_rms);
    {
        int tot = E_*24*ND;
        k_fold<<<(tot+255)/256,256,0,stream>>>(phi_pre_w, phi_post_w, phi_res_w,
                                               mhc_norm_w, alpha_pre, alpha_post, alpha_res, Wall);
    }
    k_mm_pre<<<dim3(BT/128, 3),256,0,stream>>>(s_in, Wall, inv_rms, preact);
    k_act<<<(BT*E_)/256,256,0,stream>>>(preact, b_pre, b_post, b_res, Hpre, Hpost, Hres);
    k_build<<<BT/256,256,0,stream>>>(gate_out, cnt, idx);

    const int MT = BT/128;             // 32 m-tiles (early-exit past cnt)
    const int NT_D = D_/128;           // 8
    const int NT_F = (DFFN+127)/128;   // 13

    for (int e=0; e<E_; e++){
        k_hn<<<BT,256,0,stream>>>(s_in, Hpre, sw_norm_w, cnt+e, idx+(size_t)e*BT, hn, e);
        k_mm<1><<<dim3(MT,NT_D),256,0,stream>>>(
            hn, wd_w + (size_t)e*D_*D_, Abuf, nullptr, cnt+e, D_, D_, D_);
        k_mm<2><<<dim3(MT,NT_D),256,0,stream>>>(
            Abuf, wu_w + (size_t)e*D_*D_, gsig, nullptr, cnt+e, D_, D_, D_);
        k_mm<1><<<dim3(MT,NT_F),256,0,stream>>>(
            hn, gate_w + (size_t)e*DFFN*D_, tmpP, nullptr, cnt+e, DFFN, D_, DFFN);
        k_mm<3><<<dim3(MT,NT_F),256,0,stream>>>(
            hn, up_w + (size_t)e*DFFN*D_, Pbuf, tmpP, cnt+e, DFFN, D_, DFFN);
        k_mm<3><<<dim3(MT,NT_D),256,0,stream>>>(
            Pbuf, down_w + (size_t)e*D_*DFFN, outc, gsig, cnt+e, D_, DFFN, D_);
        k_accum<<<BT,256,0,stream>>>(s_in, gate_out, Hres, Hpost, outc, cnt+e, idx+(size_t)e*BT, out_stream, e);
    }
}